// Round 12
// baseline (187.949 us; speedup 1.0000x reference)
//
#include <hip/hip_runtime.h>

// GlobalAttentionPooling: tensor_square_0e -> selu -> @W -> segment softmax -> weighted segment sum
// N nodes, 80 f32 ft (32 scalar + 16 x 3-vec), NG=1024 graphs (sorted batch_index), F=664.
//
// Math identities (validated rounds 1-4, absmax 3.9e-3):
//   selu const term cancels in softmax; pre-scale s by sqrt(log2e), v by sqrt(log2e/sqrt3)
//   so pair products are f*log2e -> exp2 directly. out_g = (sum nf*ex)/z_g.
//
// Round-17: 4 lanes/node. r16 (clean pair-split) confirmed the TLP lever: occ 37->48,
//   main 84->74.5, WRITE clean. This round doubles again: lane r=tid&3 owns rows i=4k+r.
//   (a) lane-dep s2 index solved via two-level cndmask between STATIC registers
//       (rhi ? s2[2k+1] : s2[2k], then .x/.y) -- no dynamic indexing (rule #20).
//   (b) 4 parity rows would be 128B apart = true 4-way bank conflict -> W tables re-padded
//       to stride 17 f2 (scalar) / 9 f2 (vector): rows land 8 banks apart, conflict-free
//       (also kills r16's residual 2.4M conflict cycles).
//   Garbage q=2k starts for r>=2 killed by W zero-pads. Per-lane triangle 172->92 f2-iters,
//   balanced. TPB=512/NPB=128: phase 2 VERBATIM r16 (same 281K flush sites -> WRITE ~19MB).
//   18750 waves, 8-wave blocks, expect VGPR<=64 -> up to 32 waves/CU.
//   Falsifiers: WRITE>35MB = allocator flip; conflicts>=2M = swizzle wrong; occ~75 but
//   main>=70 = TLP lever saturated (near structural floor).

typedef float f2 __attribute__((ext_vector_type(2)));

#define C0 32
#define C1 16
#define NODE_F 80
#define NG_CONST 1024
#define NPB 128                 // nodes per block
#define TPB 512                 // 4 lanes per node
#define NCHUNK 6                // phase-2 node chunks (NCHUNK*20 <= TPB)

#define SELU_SCALE 1.0507009873554804934193349852946
#define SELU_ALPHA 1.6732632423543772848170429916717
#define LOG2E      1.4426950408889634073599246810019

#define CS_SCALE 1.2011224087864498f    // sqrt(log2e)
#define CV_SCALE 0.91271231102878545f   // sqrt(log2e/sqrt(3))

// ws float layout:
//   [0, 81920)        S accum: [1024 graphs][80 ch]
//   [81920, 82944)    z accum: [1024]
//   [82944, 84320)    Wpad: 544 f2 scalar (32 rows x 17, q=16 pad) then
//                           144 f2 vector (16 rows x 9, q=8 pad)
#define WS_S 0
#define WS_Z 81920
#define WS_W 82944

__device__ __forceinline__ int ks_idx(int i, int j) { return i * C0 - (i * (i - 1)) / 2 + (j - i); }
__device__ __forceinline__ int kv_idx(int i, int j) { return 528 + i * C1 - (i * (i - 1)) / 2 + (j - i); }

// zero the accumulators + build padded (bank-swizzled) W tables
__global__ __launch_bounds__(256) void prep_kernel(
    const float* __restrict__ W, float* __restrict__ ws)
{
    const int t = blockIdx.x * blockDim.x + threadIdx.x;
    if (t < 82944) {
        ws[t] = 0.0f;                       // S and z
    } else {
        int u = t - 82944;
        if (u < 1088) {                     // scalar table: 544 f2, stride 17
            int fu = u >> 1, comp = u & 1;
            int i = fu / 17, q = fu % 17;
            float val = 0.0f;
            if (q < 16) {
                int j = 2 * q + comp;
                val = (j >= i) ? W[ks_idx(i, j)] : 0.0f;
            }
            ws[WS_W + u] = val;
        } else if (u < 1376) {              // vector table: 144 f2, stride 9
            int v = u - 1088;
            int fv = v >> 1, comp = v & 1;
            int i = fv / 9, q = fv % 9;
            float val = 0.0f;
            if (q < 8) {
                int j = 2 * q + comp;
                val = (j >= i) ? W[kv_idx(i, j)] : 0.0f;
            }
            ws[WS_W + u] = val;
        }
    }
}

__global__ __launch_bounds__(TPB, 4) void main_kernel(
    const float* __restrict__ nf, const int* __restrict__ bi,
    const float* __restrict__ ws, float* __restrict__ S,
    float* __restrict__ z, int N)
{
    __shared__ __align__(16) float Wlds[1376];
    __shared__ float exl[NPB];
    __shared__ int   bil[NPB];

    const int tid  = threadIdx.x;
    const int base = blockIdx.x * NPB;
    const float4* g4 = (const float4*)nf;

    for (int u = tid; u < 1376; u += TPB) Wlds[u] = ws[WS_W + u];

    if (tid < NPB) {
        int idx = base + tid;
        bil[tid] = bi[idx > N - 1 ? N - 1 : idx];
    }

    const int  ln    = tid >> 2;            // local node 0..127
    const int  r     = tid & 3;             // parity: rows i = 4k + r
    const bool rhi   = (r >= 2);
    const bool rodd  = (r & 1) != 0;
    const int  n     = base + ln;
    const bool valid = (n < N);
    const int  nn    = valid ? n : (N - 1);
    __syncthreads();                        // Wlds + bil ready

    const float4* gp = g4 + (size_t)nn * 20;
    const f2* WsL = (const f2*)Wlds;          // 544 f2, rows stride 17
    const f2* WvL = (const f2*)(Wlds + 1088); // 144 f2, rows stride 9

    // ---- phase 1: scalar half -> s2 in registers, PINNED (r12/r16 recipe) ----
    f2 s2[C0 / 2];
    {
        float4 rs[8];
        #pragma unroll
        for (int q = 0; q < 8; ++q) rs[q] = gp[q];
        #pragma unroll
        for (int q = 0; q < 8; ++q) {
            s2[2 * q]     = f2{rs[q].x, rs[q].y} * CS_SCALE;
            s2[2 * q + 1] = f2{rs[q].z, rs[q].w} * CS_SCALE;
        }
    }
    #pragma unroll
    for (int q = 0; q < C0 / 2; ++q) asm volatile("" : "+v"(s2[q]));

    f2 accA[2], accB[2];
    accA[0] = (f2)0.f; accA[1] = (f2)0.f; accB[0] = (f2)0.f; accB[1] = (f2)0.f;

    // scalar triangle: lane handles rows i = 4k+r, k=0..7 (72 f2-iters per lane, balanced)
    #pragma unroll
    for (int k = 0; k < 8; ++k) {
        const f2 sp = rhi ? s2[2 * k + 1] : s2[2 * k];   // static-index cndmask select
        const float si = rodd ? sp.y : sp.x;
        const f2 si2 = f2{si, si};
        #pragma unroll
        for (int q = 2 * k; q < 16; ++q) {   // q=2k garbage for r>=2 killed by W zero-pad
            f2 f = si2 * s2[q];
            f2 pp = __builtin_elementwise_max(f, (f2)0.f);
            f2 m  = __builtin_elementwise_min(f, (f2)0.f);
            f2 e; e.x = __builtin_amdgcn_exp2f(m.x);
                  e.y = __builtin_amdgcn_exp2f(m.y);
            f2 w = WsL[(4 * k + r) * 17 + q];   // 4 rows/wave, stride-17 swizzle: 8 banks apart
            accA[q & 1] = __builtin_elementwise_fma(w, pp, accA[q & 1]);
            accB[q & 1] = __builtin_elementwise_fma(w, e, accB[q & 1]);
        }
    }

    // vector half: load AFTER scalar triangle (s2 pressure window closed)
    float4 rv[12];
    #pragma unroll
    for (int q = 0; q < 12; ++q) rv[q] = gp[8 + q];

    f2 vp[C1 / 2][3];
    {
        const float* rvf = (const float*)rv;
        #pragma unroll
        for (int q = 0; q < C1 / 2; ++q) {
            #pragma unroll
            for (int c = 0; c < 3; ++c)
                vp[q][c] = f2{rvf[6 * q + c], rvf[6 * q + 3 + c]} * CV_SCALE;
        }
    }

    // vector triangle: lane handles rows i = 4k+r, k=0..3 (20 f2-iters per lane)
    #pragma unroll
    for (int k = 0; k < 4; ++k) {
        const f2 a0 = rhi ? vp[2 * k + 1][0] : vp[2 * k][0];
        const f2 a1 = rhi ? vp[2 * k + 1][1] : vp[2 * k][1];
        const f2 a2 = rhi ? vp[2 * k + 1][2] : vp[2 * k][2];
        const float vi0 = rodd ? a0.y : a0.x;
        const float vi1 = rodd ? a1.y : a1.x;
        const float vi2 = rodd ? a2.y : a2.x;
        #pragma unroll
        for (int q = 2 * k; q < 8; ++q) {    // q=2k garbage for r>=2 killed by W zero-pad
            f2 f = vp[q][0] * f2{vi0, vi0};
            f = __builtin_elementwise_fma(vp[q][1], f2{vi1, vi1}, f);
            f = __builtin_elementwise_fma(vp[q][2], f2{vi2, vi2}, f);
            f2 pp = __builtin_elementwise_max(f, (f2)0.f);
            f2 m  = __builtin_elementwise_min(f, (f2)0.f);
            f2 e; e.x = __builtin_amdgcn_exp2f(m.x);
                  e.y = __builtin_amdgcn_exp2f(m.y);
            f2 w = WvL[(4 * k + r) * 9 + q]; // stride-9 swizzle: conflict-free
            accA[q & 1] = __builtin_elementwise_fma(w, pp, accA[q & 1]);
            accB[q & 1] = __builtin_elementwise_fma(w, e, accB[q & 1]);
        }
    }

    float A1 = accA[0].x + accA[0].y + accA[1].x + accA[1].y;
    float A2 = accB[0].x + accB[0].y + accB[1].x + accB[1].y;
    A1 += __shfl_xor(A1, 1);  A1 += __shfl_xor(A1, 2);   // combine 4-lane group
    A2 += __shfl_xor(A2, 1);  A2 += __shfl_xor(A2, 2);
    const float l2 = fmaf((float)SELU_SCALE, A1,
                          (float)(SELU_SCALE * SELU_ALPHA * LOG2E) * A2);
    if (r == 0) exl[ln] = valid ? __builtin_amdgcn_exp2f(l2) : 0.0f;
    __syncthreads();

    // ---- phase 2 (tid<120): VERBATIM r12/r16 -- 6 chunks x 20 cols, flush per graph run ----
    if (tid < NCHUNK * 20) {
        const int no = tid / 20;       // 0..5
        const int c4 = tid % 20;
        const int nb = (no * NPB) / NCHUNK;
        const int ne = ((no + 1) * NPB) / NCHUNK;
        int cg = bil[nb];
        float4 acc = make_float4(0.f, 0.f, 0.f, 0.f);
        float  zacc = 0.0f;

        for (int nl = nb; nl < ne; ++nl) {
            const int g2 = bil[nl];
            if (g2 != cg) {
                unsafeAtomicAdd(&S[cg * NODE_F + c4 * 4 + 0], acc.x);
                unsafeAtomicAdd(&S[cg * NODE_F + c4 * 4 + 1], acc.y);
                unsafeAtomicAdd(&S[cg * NODE_F + c4 * 4 + 2], acc.z);
                unsafeAtomicAdd(&S[cg * NODE_F + c4 * 4 + 3], acc.w);
                if (c4 == 0) unsafeAtomicAdd(&z[cg], zacc);
                acc = make_float4(0.f, 0.f, 0.f, 0.f); zacc = 0.0f; cg = g2;
            }
            int idx = base + nl; if (idx > N - 1) idx = N - 1;   // pad nodes have w=0
            const float  w = exl[nl];
            const float4 v = g4[(size_t)idx * 20 + c4];
            acc.x = fmaf(v.x, w, acc.x); acc.y = fmaf(v.y, w, acc.y);
            acc.z = fmaf(v.z, w, acc.z); acc.w = fmaf(v.w, w, acc.w);
            zacc += w;
        }
        unsafeAtomicAdd(&S[cg * NODE_F + c4 * 4 + 0], acc.x);
        unsafeAtomicAdd(&S[cg * NODE_F + c4 * 4 + 1], acc.y);
        unsafeAtomicAdd(&S[cg * NODE_F + c4 * 4 + 2], acc.z);
        unsafeAtomicAdd(&S[cg * NODE_F + c4 * 4 + 3], acc.w);
        if (c4 == 0) unsafeAtomicAdd(&z[cg], zacc);
    }
}

__global__ __launch_bounds__(256) void divide_kernel(
    const float* __restrict__ S, const float* __restrict__ z,
    float* __restrict__ out)
{
    const int t = blockIdx.x * blockDim.x + threadIdx.x;
    if (t >= NG_CONST * NODE_F) return;
    const float zz = z[t / NODE_F];
    out[t] = (zz > 0.0f) ? (S[t] / zz) : 0.0f;
}

extern "C" void kernel_launch(void* const* d_in, const int* in_sizes, int n_in,
                              void* d_out, int out_size, void* d_ws, size_t ws_size,
                              hipStream_t stream) {
    const float* nf = (const float*)d_in[0];   // (N, 80) f32
    const int*   bi = (const int*)d_in[1];     // (N,) i32 sorted
    // d_in[2] = num_graphs (static 1024)
    const float* W  = (const float*)d_in[3];   // (664,) f32
    float* out = (float*)d_out;

    const int N = in_sizes[0] / NODE_F;
    float* ws = (float*)d_ws;
    float* S  = ws + WS_S;
    float* z  = ws + WS_Z;

    hipLaunchKernelGGL(prep_kernel, dim3(332), dim3(256), 0, stream, W, ws);
    hipLaunchKernelGGL(main_kernel, dim3((N + NPB - 1) / NPB), dim3(TPB), 0, stream,
                       nf, bi, ws, S, z, N);
    hipLaunchKernelGGL(divide_kernel, dim3((NG_CONST * NODE_F + 255) / 256), dim3(256),
                       0, stream, S, z, out);
}